// Round 12
// baseline (528.974 us; speedup 1.0000x reference)
//
#include <hip/hip_runtime.h>
#include <hip/hip_cooperative_groups.h>
#include <math.h>

namespace cg = cooperative_groups;

// B=4, T=2048, C=768, H=64
#define TB 2048
#define CB 768
#define NB 4
#define NROWS (NB * TB) // 8192
#define SKV 6           // proj K-split
#define KSTEPS 2        // CB / (64*SKV)
#define NSMAX 32        // max KV splits per row (T/64)
#define WGPB 528        // per-batch attn jobs: sum_{g=0..31}(g+1)
#define NWG 1024        // cooperative grid size

typedef __attribute__((ext_vector_type(8))) short bf16x8;
typedef __attribute__((ext_vector_type(4))) float f32x4;
typedef __attribute__((ext_vector_type(2))) float f32x2;
typedef __attribute__((ext_vector_type(2))) unsigned int u32x2;
typedef __attribute__((ext_vector_type(4))) unsigned int u32x4;

__device__ inline unsigned short f2bf(float f) {
  union { float f; unsigned u; } v; v.f = f;
  unsigned r = v.u + 0x7FFFu + ((v.u >> 16) & 1u);
  return (unsigned short)(r >> 16);
}
__device__ inline unsigned pack2bf(float a, float b) {
  return (unsigned)f2bf(a) | ((unsigned)f2bf(b) << 16);
}
__device__ inline float bf2f(unsigned short u) {
  union { unsigned u; float f; } v; v.u = (unsigned)u << 16; return v.f;
}

// shared-memory union used by all phases (max 16640 B)
union __align__(16) SMU {
  float tw[64][65];
  unsigned short xs[64 * 64];
  float tr[64][17];
  struct { char k[8192]; char v[8192]; } kv;
};

// ============ phase bodies (verbatim from R11-verified kernels) ==============

__device__ __forceinline__ void cvt_body(SMU& sm, int bx, int by,
                                         const float* __restrict__ Wq,
                                         const float* __restrict__ Wk,
                                         const float* __restrict__ Wv,
                                         unsigned short* __restrict__ Wt, int tid) {
  const float* W = (by == 0) ? Wq : (by == 1) ? Wk : Wv;
  const int c0 = bx * 64;
  const int row = tid >> 2, seg = tid & 3;
#pragma unroll
  for (int i = 0; i < 4; ++i) {
    float4 f = *(const float4*)(W + (size_t)(c0 + row) * 64 + seg * 16 + i * 4);
    sm.tw[row][seg * 16 + i * 4 + 0] = f.x;
    sm.tw[row][seg * 16 + i * 4 + 1] = f.y;
    sm.tw[row][seg * 16 + i * 4 + 2] = f.z;
    sm.tw[row][seg * 16 + i * 4 + 3] = f.w;
  }
  __syncthreads();
  const int j = tid >> 2, cq = tid & 3;
  unsigned short* dst = Wt + (size_t)(by * 64 + j) * CB + c0 + cq * 16;
  u32x4 ua, ub;
#pragma unroll
  for (int i = 0; i < 4; ++i)
    ua[i] = pack2bf(sm.tw[cq * 16 + 2 * i][j], sm.tw[cq * 16 + 2 * i + 1][j]);
#pragma unroll
  for (int i = 0; i < 4; ++i)
    ub[i] = pack2bf(sm.tw[cq * 16 + 8 + 2 * i][j], sm.tw[cq * 16 + 9 + 2 * i][j]);
  *(u32x4*)dst = ua;
  *(u32x4*)(dst + 8) = ub;
  __syncthreads();
}

__device__ __forceinline__ void proj_body(SMU& sm, int m0, int ks,
                                          const float* __restrict__ x,
                                          const unsigned short* __restrict__ Wt,
                                          unsigned short* __restrict__ part, int tid) {
  const int wv = tid >> 6;
  const int l = tid & 63;
  const int lrow = l & 15, lg = l >> 4;
  const int kbase = ks * KSTEPS * 64;
  const int srow = tid >> 2;
  const int sq = tid & 3;
  const float* xp = x + (size_t)(m0 + srow) * CB + sq * 16;

  f32x4 acc[4][3];
#pragma unroll
  for (int a = 0; a < 4; ++a)
#pragma unroll
    for (int n = 0; n < 3; ++n) acc[a][n] = (f32x4){0.f, 0.f, 0.f, 0.f};

  for (int kk = 0; kk < KSTEPS; ++kk) {
    int k0 = kbase + kk * 64;
    bf16x8 c0, c1;
#pragma unroll
    for (int i = 0; i < 2; ++i) {
      float4 f = *(const float4*)(xp + k0 + 4 * i);
      c0[4 * i + 0] = (short)f2bf(f.x); c0[4 * i + 1] = (short)f2bf(f.y);
      c0[4 * i + 2] = (short)f2bf(f.z); c0[4 * i + 3] = (short)f2bf(f.w);
    }
#pragma unroll
    for (int i = 0; i < 2; ++i) {
      float4 f = *(const float4*)(xp + k0 + 8 + 4 * i);
      c1[4 * i + 0] = (short)f2bf(f.x); c1[4 * i + 1] = (short)f2bf(f.y);
      c1[4 * i + 2] = (short)f2bf(f.z); c1[4 * i + 3] = (short)f2bf(f.w);
    }
    {
      char* base = (char*)sm.xs + srow * 128;
      int swz = (srow & 7) << 4;
      *(bf16x8*)(base + ((sq * 32 + 0) ^ swz)) = c0;
      *(bf16x8*)(base + ((sq * 32 + 16) ^ swz)) = c1;
    }
    __syncthreads();

#pragma unroll
    for (int s = 0; s < 2; ++s) {
      bf16x8 af[4], bfr[3];
#pragma unroll
      for (int mf = 0; mf < 4; ++mf) {
        int r = mf * 16 + lrow;
        af[mf] = *(const bf16x8*)((const char*)sm.xs + r * 128 +
                                  ((s * 64 + lg * 16) ^ ((r & 7) << 4)));
      }
#pragma unroll
      for (int nf = 0; nf < 3; ++nf) {
        int col = wv * 48 + nf * 16 + lrow;
        bfr[nf] = *(const bf16x8*)(Wt + (size_t)col * CB + k0 + s * 32 + lg * 8);
      }
#pragma unroll
      for (int mf = 0; mf < 4; ++mf)
#pragma unroll
        for (int nf = 0; nf < 3; ++nf)
          acc[mf][nf] = __builtin_amdgcn_mfma_f32_16x16x32_bf16(af[mf], bfr[nf], acc[mf][nf], 0, 0, 0);
    }
    __syncthreads();
  }

  unsigned short* pb = part + (size_t)ks * NROWS * 192;
#pragma unroll
  for (int mf = 0; mf < 4; ++mf)
#pragma unroll
    for (int nf = 0; nf < 3; ++nf)
#pragma unroll
      for (int r = 0; r < 4; ++r) {
        int grow = m0 + mf * 16 + lg * 4 + r;
        int j = wv * 48 + nf * 16 + lrow;
        pb[(size_t)grow * 192 + j] = f2bf(acc[mf][nf][r]);
      }
}

__device__ __forceinline__ void reduce_body(SMU& sm, int vw,
                                            const unsigned short* __restrict__ part,
                                            unsigned short* __restrict__ q,
                                            unsigned short* __restrict__ k,
                                            unsigned short* __restrict__ vT, int tid) {
  if (vw < 4096) {
    int id = vw * 256 + tid;
    int row = id >> 7, col = id & 127;
    float s = 0.f;
#pragma unroll
    for (int ks = 0; ks < SKV; ++ks)
      s += bf2f(part[((size_t)ks * NROWS + row) * 192 + col]);
    unsigned short v = f2bf(s);
    if (col < 64) q[(size_t)row * 64 + col] = v;
    else          k[(size_t)row * 64 + (col - 64)] = v;
  } else {
    int bid = vw - 4096;
    const int t0 = (bid & 127) * 16;
    const int b = bid >> 7;
    const int c = tid & 63, trow = tid >> 6;
#pragma unroll
    for (int p = 0; p < 4; ++p) {
      int tl = p * 4 + trow;
      int row = b * TB + t0 + tl;
      float s = 0.f;
#pragma unroll
      for (int ks = 0; ks < SKV; ++ks)
        s += bf2f(part[((size_t)ks * NROWS + row) * 192 + 128 + c]);
      sm.tr[c][tl] = s;
    }
    __syncthreads();
    const int h = tid >> 2, tq = tid & 3;
    u32x2 pk;
    pk.x = pack2bf(sm.tr[h][tq * 4 + 0], sm.tr[h][tq * 4 + 1]);
    pk.y = pack2bf(sm.tr[h][tq * 4 + 2], sm.tr[h][tq * 4 + 3]);
    *(u32x2*)(vT + ((size_t)(b * 64 + h)) * TB + t0 + tq * 4) = pk;
    __syncthreads();
  }
}

__device__ __forceinline__ void attn_body(SMU& sm, int w, int b,
                                          const unsigned short* __restrict__ q,
                                          const unsigned short* __restrict__ k,
                                          const unsigned short* __restrict__ vT,
                                          unsigned short* __restrict__ PO,
                                          float* __restrict__ Mp, float* __restrict__ Lp,
                                          int tid) {
  const int wid = tid >> 6, l = tid & 63;
  const int lrow = l & 15, lg = l >> 4;

  int g = (int)((sqrtf((float)(8 * w + 1)) - 1.f) * 0.5f);
  while ((g + 1) * (g + 2) / 2 <= w) ++g;
  while (g * (g + 1) / 2 > w) --g;
  const int blk = w - g * (g + 1) / 2;
  const int kv0 = blk * 64;
  const bool last = (blk == g);
  const int qrow = (4 * g + wid) * 16 + lrow;

  const unsigned short* qb = q + (size_t)b * TB * 64;
  const char* kbb = (const char*)(k + (size_t)b * TB * 64);
  const unsigned short* vb = vT + (size_t)b * 64 * TB;

  const int srow = tid >> 2;
  const int sc = (tid & 3) * 32;
  float4 kg0 = *(const float4*)(kbb + (size_t)kv0 * 128 + tid * 32);
  float4 kg1 = *(const float4*)(kbb + (size_t)kv0 * 128 + tid * 32 + 16);
  const char* vrow = (const char*)(vb + (size_t)srow * TB + kv0);
  float4 vg0 = *(const float4*)(vrow + sc);
  float4 vg1 = *(const float4*)(vrow + sc + 16);

  bf16x8 qf[2];
#pragma unroll
  for (int s = 0; s < 2; ++s)
    qf[s] = *(const bf16x8*)(qb + (size_t)qrow * 64 + s * 32 + lg * 8);

  {
    const int kswz_w = (srow & 7) << 4;
    *(float4*)(sm.kv.k + srow * 128 + ((sc + 0) ^ kswz_w)) = kg0;
    *(float4*)(sm.kv.k + srow * 128 + ((sc + 16) ^ kswz_w)) = kg1;
    const int vswz_w = (srow & 3) << 5;
    *(float4*)(sm.kv.v + srow * 128 + ((sc + 0) ^ vswz_w)) = vg0;
    *(float4*)(sm.kv.v + srow * 128 + ((sc + 16) ^ vswz_w)) = vg1;
  }
  __syncthreads();

  const int kswz = (lrow & 7) << 4;
  f32x4 S[4];
#pragma unroll
  for (int cf = 0; cf < 4; ++cf) S[cf] = (f32x4){0.f, 0.f, 0.f, 0.f};
#pragma unroll
  for (int cf = 0; cf < 4; ++cf) {
    const char* kp = sm.kv.k + (cf * 16 + lrow) * 128;
#pragma unroll
    for (int s = 0; s < 2; ++s) {
      bf16x8 kf = *(const bf16x8*)(kp + ((s * 64 + lg * 16) ^ kswz));
      S[cf] = __builtin_amdgcn_mfma_f32_16x16x32_bf16(kf, qf[s], S[cf], 0, 0, 0);
    }
  }

  const float scale = 0.03608439182435161f; // 768^-0.5
  float tmx = -INFINITY;
#pragma unroll
  for (int cf = 0; cf < 4; ++cf)
#pragma unroll
    for (int r = 0; r < 4; ++r) {
      float vv = S[cf][r] * scale;
      if (last) {
        int kvi = kv0 + cf * 16 + lg * 4 + r;
        vv = (kvi > qrow) ? -INFINITY : vv;
      }
      S[cf][r] = vv;
      tmx = fmaxf(tmx, vv);
    }
  tmx = fmaxf(tmx, __shfl_xor(tmx, 16));
  tmx = fmaxf(tmx, __shfl_xor(tmx, 32));

  float lsl = 0.f;
  float p[4][4];
#pragma unroll
  for (int cf = 0; cf < 4; ++cf)
#pragma unroll
    for (int r = 0; r < 4; ++r) {
      float pe = __expf(S[cf][r] - tmx);
      p[cf][r] = pe;
      lsl += pe;
    }
  union { unsigned u[4]; bf16x8 v; } pbu[2];
#pragma unroll
  for (int s = 0; s < 2; ++s) {
    pbu[s].u[0] = pack2bf(p[2 * s][0], p[2 * s][1]);
    pbu[s].u[1] = pack2bf(p[2 * s][2], p[2 * s][3]);
    pbu[s].u[2] = pack2bf(p[2 * s + 1][0], p[2 * s + 1][1]);
    pbu[s].u[3] = pack2bf(p[2 * s + 1][2], p[2 * s + 1][3]);
  }

  f32x4 o[4];
#pragma unroll
  for (int hf = 0; hf < 4; ++hf) o[hf] = (f32x4){0.f, 0.f, 0.f, 0.f};
  const int rswz = (lrow & 3) << 5;
#pragma unroll
  for (int s = 0; s < 2; ++s)
#pragma unroll
    for (int hf = 0; hf < 4; ++hf) {
      int r = hf * 16 + lrow;
      int a1 = r * 128 + ((s * 64 + lg * 8) ^ rswz);
      u32x2 lo = *(const u32x2*)(sm.kv.v + a1);
      u32x2 hi = *(const u32x2*)(sm.kv.v + (a1 ^ 32));
      union { unsigned u[4]; bf16x8 v; } vfu;
      vfu.u[0] = lo.x; vfu.u[1] = lo.y; vfu.u[2] = hi.x; vfu.u[3] = hi.y;
      o[hf] = __builtin_amdgcn_mfma_f32_16x16x32_bf16(vfu.v, pbu[s].v, o[hf], 0, 0, 0);
    }

  float ls = lsl;
  ls += __shfl_xor(ls, 16);
  ls += __shfl_xor(ls, 32);

  size_t rowg = (size_t)blk * NROWS + b * TB + qrow;
  unsigned short* pop = PO + rowg * 64 + lg * 4;
#pragma unroll
  for (int hf = 0; hf < 4; ++hf) {
    u32x2 pk;
    pk.x = pack2bf(o[hf][0], o[hf][1]);
    pk.y = pack2bf(o[hf][2], o[hf][3]);
    *(u32x2*)(pop + hf * 16) = pk;
  }
  if (lg == 0) {
    Mp[rowg] = tmx;
    Lp[rowg] = ls;
  }
  __syncthreads(); // protect LDS reuse by next virtual job
}

// attn_reduce: 32 threads/row (2 h each), unrolled-4 split loop
__device__ __forceinline__ void attnred_body(int id, const unsigned short* __restrict__ PO,
                                             const float* __restrict__ Mp,
                                             const float* __restrict__ Lp,
                                             float* __restrict__ out) {
  int row = id >> 5, h0 = (id & 31) * 2;
  int t = row & (TB - 1);
  int ns = (t >> 6) + 1;
  float M = -INFINITY;
#pragma unroll 4
  for (int s = 0; s < ns; ++s) M = fmaxf(M, Mp[(size_t)s * NROWS + row]);
  float L = 0.f, a0 = 0.f, a1 = 0.f;
#pragma unroll 4
  for (int s = 0; s < ns; ++s) {
    float w = __expf(Mp[(size_t)s * NROWS + row] - M);
    L += Lp[(size_t)s * NROWS + row] * w;
    unsigned pv = *(const unsigned*)(PO + ((size_t)s * NROWS + row) * 64 + h0);
    a0 += bf2f((unsigned short)(pv & 0xffff)) * w;
    a1 += bf2f((unsigned short)(pv >> 16)) * w;
  }
  float rL = 1.f / L;
  f32x2 r; r.x = a0 * rL; r.y = a1 * rL;
  *(f32x2*)(out + (size_t)row * 64 + h0) = r;
}

// ===================== fused cooperative kernel ==============================
__launch_bounds__(256, 4)
__global__ void fused_kernel(const float* x, const float* Wq, const float* Wk,
                             const float* Wv, unsigned short* Wt, unsigned short* qb,
                             unsigned short* kb, unsigned short* vT,
                             unsigned short* partPO, float* Mp, float* Lp, float* out) {
  cg::grid_group grid = cg::this_grid();
  __shared__ SMU sm;
  const int wg = blockIdx.x;
  const int tid = threadIdx.x;

  // phase 1: weight transpose (36 jobs)
  if (wg < 36) cvt_body(sm, wg % 12, wg / 12, Wq, Wk, Wv, Wt, tid);
  grid.sync();
  // phase 2: projection GEMM (768 jobs = 128 m-tiles x 6 k-splits)
  if (wg < 768) proj_body(sm, (wg & 127) * 64, wg >> 7, x, Wt, partPO, tid);
  grid.sync();
  // phase 3: reduce to q/k/vT (4608 jobs)
  for (int vw = wg; vw < 4608; vw += NWG)
    reduce_body(sm, vw, partPO, qb, kb, vT, tid);
  grid.sync();
  // phase 4: attention (2112 jobs = 528 x 4 batches)
  for (int vw = wg; vw < WGPB * NB; vw += NWG)
    attn_body(sm, vw % WGPB, vw / WGPB, qb, kb, vT, partPO, Mp, Lp, tid);
  grid.sync();
  // phase 5: combine splits (NROWS*32 = 262144 items)
  {
    int id = wg * 256 + tid;
    attnred_body(id, partPO, Mp, Lp, out);
  }
}

// ===================== fallback standalone kernels ===========================
__global__ void cvt_w_kernel(const float* __restrict__ Wq, const float* __restrict__ Wk,
                             const float* __restrict__ Wv, unsigned short* __restrict__ Wt) {
  __shared__ SMU sm;
  cvt_body(sm, blockIdx.x, blockIdx.y, Wq, Wk, Wv, Wt, threadIdx.x);
}
__launch_bounds__(256)
__global__ void proj_kernel(const float* __restrict__ x, const unsigned short* __restrict__ Wt,
                            unsigned short* __restrict__ part) {
  __shared__ SMU sm;
  proj_body(sm, blockIdx.x * 64, blockIdx.y, x, Wt, part, threadIdx.x);
}
__global__ void reduce_qkv_kernel(const unsigned short* __restrict__ part,
                                  unsigned short* __restrict__ q, unsigned short* __restrict__ k,
                                  unsigned short* __restrict__ vT) {
  __shared__ SMU sm;
  reduce_body(sm, blockIdx.x, part, q, k, vT, threadIdx.x);
}
__launch_bounds__(256)
__global__ void attn_kernel(const unsigned short* __restrict__ q,
                            const unsigned short* __restrict__ k,
                            const unsigned short* __restrict__ vT,
                            unsigned short* __restrict__ PO, float* __restrict__ Mp,
                            float* __restrict__ Lp) {
  __shared__ SMU sm;
  attn_body(sm, blockIdx.x, blockIdx.y, q, k, vT, PO, Mp, Lp, threadIdx.x);
}
__global__ void attn_reduce_kernel(const unsigned short* __restrict__ PO,
                                   const float* __restrict__ Mp,
                                   const float* __restrict__ Lp,
                                   float* __restrict__ out) {
  attnred_body(blockIdx.x * 256 + threadIdx.x, PO, Mp, Lp, out);
}

extern "C" void kernel_launch(void* const* d_in, const int* in_sizes, int n_in,
                              void* d_out, int out_size, void* d_ws, size_t ws_size,
                              hipStream_t stream) {
  const float* x  = (const float*)d_in[0];
  const float* Wq = (const float*)d_in[1];
  const float* Wk = (const float*)d_in[2];
  const float* Wv = (const float*)d_in[3];
  float* out = (float*)d_out;

  unsigned short* Wt = (unsigned short*)d_ws;
  unsigned short* qb = Wt + 192 * CB;
  unsigned short* kb = qb + (size_t)NROWS * 64;
  unsigned short* vT = kb + (size_t)NROWS * 64;
  char* scratch = (char*)(vT + (size_t)NROWS * 64);

  unsigned short* partPO = (unsigned short*)scratch;
  float* Mp = (float*)(scratch + (size_t)NSMAX * NROWS * 64 * 2);
  float* Lp = Mp + (size_t)NSMAX * NROWS;

  void* args[12];
  args[0] = (void*)&x;   args[1] = (void*)&Wq;  args[2] = (void*)&Wk;
  args[3] = (void*)&Wv;  args[4] = (void*)&Wt;  args[5] = (void*)&qb;
  args[6] = (void*)&kb;  args[7] = (void*)&vT;  args[8] = (void*)&partPO;
  args[9] = (void*)&Mp;  args[10] = (void*)&Lp; args[11] = (void*)&out;

  hipError_t err = hipLaunchCooperativeKernel((const void*)fused_kernel,
                                              dim3(NWG), dim3(256), args, 0, stream);
  if (err != hipSuccess) {
    // fallback: same bodies as five sequential kernels
    hipLaunchKernelGGL(cvt_w_kernel, dim3(12, 3), dim3(256), 0, stream, Wq, Wk, Wv, Wt);
    hipLaunchKernelGGL(proj_kernel, dim3(NROWS / 64, SKV), dim3(256), 0, stream, x, Wt, partPO);
    hipLaunchKernelGGL(reduce_qkv_kernel, dim3(4096 + 512), dim3(256), 0, stream,
                       partPO, qb, kb, vT);
    hipLaunchKernelGGL(attn_kernel, dim3(WGPB, NB), dim3(256), 0, stream,
                       qb, kb, vT, partPO, Mp, Lp);
    hipLaunchKernelGGL(attn_reduce_kernel, dim3((NROWS * 32) / 256), dim3(256), 0, stream,
                       partPO, Mp, Lp, out);
  }
}

// Round 13
// 62.559 us; speedup vs baseline: 8.4556x; 8.4556x over previous
//
#include <hip/hip_runtime.h>
#include <math.h>

// B=4, T=2048, C=768, H=64
#define TB 2048
#define CB 768
#define NB 4
#define NROWS (NB * TB) // 8192
#define SKV 6           // proj K-split
#define NSMAX 32        // max KV splits per row (T/64)
#define WGPB 528        // per-batch attn WGs: sum_{g=0..31} (g+1)

typedef __attribute__((ext_vector_type(8))) short bf16x8;
typedef __attribute__((ext_vector_type(4))) float f32x4;
typedef __attribute__((ext_vector_type(2))) float f32x2;
typedef __attribute__((ext_vector_type(2))) unsigned int u32x2;
typedef __attribute__((ext_vector_type(4))) unsigned int u32x4;

__device__ inline unsigned short f2bf(float f) {
  union { float f; unsigned u; } v; v.f = f;
  unsigned r = v.u + 0x7FFFu + ((v.u >> 16) & 1u);
  return (unsigned short)(r >> 16);
}
__device__ inline unsigned pack2bf(float a, float b) {
  return (unsigned)f2bf(a) | ((unsigned)f2bf(b) << 16);
}
__device__ inline float bf2f(unsigned short u) {
  union { unsigned u; float f; } v; v.u = (unsigned)u << 16; return v.f;
}

// ---------------- kernel 0: weights fp32 [C][64] x3 -> Wt bf16 [192][768] ----
__global__ void cvt_w_kernel(const float* __restrict__ Wq, const float* __restrict__ Wk,
                             const float* __restrict__ Wv, unsigned short* __restrict__ Wt) {
  __shared__ float tw[64][65];
  const float* W = (blockIdx.y == 0) ? Wq : (blockIdx.y == 1) ? Wk : Wv;
  const int c0 = blockIdx.x * 64;
  const int row = threadIdx.x >> 2, seg = threadIdx.x & 3;
#pragma unroll
  for (int i = 0; i < 4; ++i) {
    float4 f = *(const float4*)(W + (size_t)(c0 + row) * 64 + seg * 16 + i * 4);
    tw[row][seg * 16 + i * 4 + 0] = f.x;
    tw[row][seg * 16 + i * 4 + 1] = f.y;
    tw[row][seg * 16 + i * 4 + 2] = f.z;
    tw[row][seg * 16 + i * 4 + 3] = f.w;
  }
  __syncthreads();
  const int j = threadIdx.x >> 2, cq = threadIdx.x & 3;
  unsigned short* dst = Wt + (size_t)(blockIdx.y * 64 + j) * CB + c0 + cq * 16;
  u32x4 ua, ub;
#pragma unroll
  for (int i = 0; i < 4; ++i) ua[i] = pack2bf(tw[cq * 16 + 2 * i][j], tw[cq * 16 + 2 * i + 1][j]);
#pragma unroll
  for (int i = 0; i < 4; ++i) ub[i] = pack2bf(tw[cq * 16 + 8 + 2 * i][j], tw[cq * 16 + 9 + 2 * i][j]);
  *(u32x4*)dst = ua;
  *(u32x4*)(dst + 8) = ub;
}

// ---------------- kernel 1: QKV projection GEMM, K-split ---------------------
__launch_bounds__(256)
__global__ void proj_kernel(const float* __restrict__ x, const unsigned short* __restrict__ Wt,
                            unsigned short* __restrict__ part, int ksteps) {
  __shared__ __align__(16) unsigned short xs[64 * 64];
  const int tid = threadIdx.x;
  const int wv = tid >> 6;
  const int l = tid & 63;
  const int lrow = l & 15, lg = l >> 4;
  const int m0 = blockIdx.x * 64;
  const int ks = blockIdx.y;
  const int kbase = ks * ksteps * 64;
  const int srow = tid >> 2;
  const int sq = tid & 3;
  const float* xp = x + (size_t)(m0 + srow) * CB + sq * 16;

  f32x4 acc[4][3];
#pragma unroll
  for (int a = 0; a < 4; ++a)
#pragma unroll
    for (int n = 0; n < 3; ++n) acc[a][n] = (f32x4){0.f, 0.f, 0.f, 0.f};

  for (int kk = 0; kk < ksteps; ++kk) {
    int k0 = kbase + kk * 64;
    bf16x8 c0, c1;
#pragma unroll
    for (int i = 0; i < 2; ++i) {
      float4 f = *(const float4*)(xp + k0 + 4 * i);
      c0[4 * i + 0] = (short)f2bf(f.x); c0[4 * i + 1] = (short)f2bf(f.y);
      c0[4 * i + 2] = (short)f2bf(f.z); c0[4 * i + 3] = (short)f2bf(f.w);
    }
#pragma unroll
    for (int i = 0; i < 2; ++i) {
      float4 f = *(const float4*)(xp + k0 + 8 + 4 * i);
      c1[4 * i + 0] = (short)f2bf(f.x); c1[4 * i + 1] = (short)f2bf(f.y);
      c1[4 * i + 2] = (short)f2bf(f.z); c1[4 * i + 3] = (short)f2bf(f.w);
    }
    {
      char* base = (char*)xs + srow * 128;
      int swz = (srow & 7) << 4;
      *(bf16x8*)(base + ((sq * 32 + 0) ^ swz)) = c0;
      *(bf16x8*)(base + ((sq * 32 + 16) ^ swz)) = c1;
    }
    __syncthreads();

#pragma unroll
    for (int s = 0; s < 2; ++s) {
      bf16x8 af[4], bfr[3];
#pragma unroll
      for (int mf = 0; mf < 4; ++mf) {
        int r = mf * 16 + lrow;
        af[mf] = *(const bf16x8*)((const char*)xs + r * 128 +
                                  ((s * 64 + lg * 16) ^ ((r & 7) << 4)));
      }
#pragma unroll
      for (int nf = 0; nf < 3; ++nf) {
        int col = wv * 48 + nf * 16 + lrow;
        bfr[nf] = *(const bf16x8*)(Wt + (size_t)col * CB + k0 + s * 32 + lg * 8);
      }
#pragma unroll
      for (int mf = 0; mf < 4; ++mf)
#pragma unroll
        for (int nf = 0; nf < 3; ++nf)
          acc[mf][nf] = __builtin_amdgcn_mfma_f32_16x16x32_bf16(af[mf], bfr[nf], acc[mf][nf], 0, 0, 0);
    }
    __syncthreads();
  }

  unsigned short* pb = part + (size_t)ks * NROWS * 192;
#pragma unroll
  for (int mf = 0; mf < 4; ++mf)
#pragma unroll
    for (int nf = 0; nf < 3; ++nf)
#pragma unroll
      for (int r = 0; r < 4; ++r) {
        int grow = m0 + mf * 16 + lg * 4 + r;
        int j = wv * 48 + nf * 16 + lrow;
        pb[(size_t)grow * 192 + j] = f2bf(acc[mf][nf][r]);
      }
}

// ---------------- kernel 1b: fused reduce (q,k and transposed v) -------------
__global__ void reduce_qkv_kernel(const unsigned short* __restrict__ part,
                                  unsigned short* __restrict__ q, unsigned short* __restrict__ k,
                                  unsigned short* __restrict__ vT, int SK) {
  __shared__ float tr[64][17];
  if (blockIdx.x < 4096) {
    int id = blockIdx.x * 256 + threadIdx.x;
    int row = id >> 7, col = id & 127;
    float s = 0.f;
    for (int ks = 0; ks < SK; ++ks)
      s += bf2f(part[((size_t)ks * NROWS + row) * 192 + col]);
    unsigned short v = f2bf(s);
    if (col < 64) q[(size_t)row * 64 + col] = v;
    else          k[(size_t)row * 64 + (col - 64)] = v;
  } else {
    int bid = blockIdx.x - 4096;
    const int t0 = (bid & 127) * 16;
    const int b = bid >> 7;
    const int c = threadIdx.x & 63, trow = threadIdx.x >> 6;
#pragma unroll
    for (int p = 0; p < 4; ++p) {
      int tl = p * 4 + trow;
      int row = b * TB + t0 + tl;
      float s = 0.f;
      for (int ks = 0; ks < SK; ++ks)
        s += bf2f(part[((size_t)ks * NROWS + row) * 192 + 128 + c]);
      tr[c][tl] = s;
    }
    __syncthreads();
    const int h = threadIdx.x >> 2, tq = threadIdx.x & 3;
    u32x2 pk;
    pk.x = pack2bf(tr[h][tq * 4 + 0], tr[h][tq * 4 + 1]);
    pk.y = pack2bf(tr[h][tq * 4 + 2], tr[h][tq * 4 + 3]);
    *(u32x2*)(vT + ((size_t)(b * 64 + h)) * TB + t0 + tq * 4) = pk;
  }
}

// ---------------- kernel 2: causal attention, 4 Q-tiles share one KV block ---
__launch_bounds__(256)
__global__ void attn_kernel(const unsigned short* __restrict__ q,
                            const unsigned short* __restrict__ k,
                            const unsigned short* __restrict__ vT,
                            unsigned short* __restrict__ PO, float* __restrict__ Mp,
                            float* __restrict__ Lp) {
  __shared__ __align__(16) char ksm[8192]; // K tile [64 kv][128B], swz (r&7)<<4
  __shared__ __align__(16) char vsm[8192]; // V tile [64 h][128B kv], swz (r&3)<<5
  const int tid = threadIdx.x;
  const int wid = tid >> 6, l = tid & 63;
  const int lrow = l & 15, lg = l >> 4;
  const int b = blockIdx.y;
  const int w = blockIdx.x;

  int g = (int)((sqrtf((float)(8 * w + 1)) - 1.f) * 0.5f);
  while ((g + 1) * (g + 2) / 2 <= w) ++g;
  while (g * (g + 1) / 2 > w) --g;
  const int blk = w - g * (g + 1) / 2;
  const int kv0 = blk * 64;
  const bool last = (blk == g);
  const int qrow = (4 * g + wid) * 16 + lrow;

  const unsigned short* qb = q + (size_t)b * TB * 64;
  const char* kbb = (const char*)(k + (size_t)b * TB * 64);
  const unsigned short* vb = vT + (size_t)b * 64 * TB;

  const int srow = tid >> 2;
  const int sc = (tid & 3) * 32;
  float4 kg0 = *(const float4*)(kbb + (size_t)kv0 * 128 + tid * 32);
  float4 kg1 = *(const float4*)(kbb + (size_t)kv0 * 128 + tid * 32 + 16);
  const char* vrow = (const char*)(vb + (size_t)srow * TB + kv0);
  float4 vg0 = *(const float4*)(vrow + sc);
  float4 vg1 = *(const float4*)(vrow + sc + 16);

  bf16x8 qf[2];
#pragma unroll
  for (int s = 0; s < 2; ++s)
    qf[s] = *(const bf16x8*)(qb + (size_t)qrow * 64 + s * 32 + lg * 8);

  {
    const int kswz_w = (srow & 7) << 4;
    *(float4*)(ksm + srow * 128 + ((sc + 0) ^ kswz_w)) = kg0;
    *(float4*)(ksm + srow * 128 + ((sc + 16) ^ kswz_w)) = kg1;
    const int vswz_w = (srow & 3) << 5;
    *(float4*)(vsm + srow * 128 + ((sc + 0) ^ vswz_w)) = vg0;
    *(float4*)(vsm + srow * 128 + ((sc + 16) ^ vswz_w)) = vg1;
  }
  __syncthreads();

  const int kswz = (lrow & 7) << 4;
  f32x4 S[4];
#pragma unroll
  for (int cf = 0; cf < 4; ++cf) S[cf] = (f32x4){0.f, 0.f, 0.f, 0.f};
#pragma unroll
  for (int cf = 0; cf < 4; ++cf) {
    const char* kp = ksm + (cf * 16 + lrow) * 128;
#pragma unroll
    for (int s = 0; s < 2; ++s) {
      bf16x8 kf = *(const bf16x8*)(kp + ((s * 64 + lg * 16) ^ kswz));
      S[cf] = __builtin_amdgcn_mfma_f32_16x16x32_bf16(kf, qf[s], S[cf], 0, 0, 0);
    }
  }

  const float scale = 0.03608439182435161f; // 768^-0.5
  float tmx = -INFINITY;
#pragma unroll
  for (int cf = 0; cf < 4; ++cf)
#pragma unroll
    for (int r = 0; r < 4; ++r) {
      float vv = S[cf][r] * scale;
      if (last) {
        int kvi = kv0 + cf * 16 + lg * 4 + r;
        vv = (kvi > qrow) ? -INFINITY : vv;
      }
      S[cf][r] = vv;
      tmx = fmaxf(tmx, vv);
    }
  tmx = fmaxf(tmx, __shfl_xor(tmx, 16));
  tmx = fmaxf(tmx, __shfl_xor(tmx, 32)); // row max

  float lsl = 0.f;
  float p[4][4];
#pragma unroll
  for (int cf = 0; cf < 4; ++cf)
#pragma unroll
    for (int r = 0; r < 4; ++r) {
      float pe = __expf(S[cf][r] - tmx);
      p[cf][r] = pe;
      lsl += pe;
    }
  union { unsigned u[4]; bf16x8 v; } pbu[2];
#pragma unroll
  for (int s = 0; s < 2; ++s) {
    pbu[s].u[0] = pack2bf(p[2 * s][0], p[2 * s][1]);
    pbu[s].u[1] = pack2bf(p[2 * s][2], p[2 * s][3]);
    pbu[s].u[2] = pack2bf(p[2 * s + 1][0], p[2 * s + 1][1]);
    pbu[s].u[3] = pack2bf(p[2 * s + 1][2], p[2 * s + 1][3]);
  }

  f32x4 o[4];
#pragma unroll
  for (int hf = 0; hf < 4; ++hf) o[hf] = (f32x4){0.f, 0.f, 0.f, 0.f};
  const int rswz = (lrow & 3) << 5;
#pragma unroll
  for (int s = 0; s < 2; ++s)
#pragma unroll
    for (int hf = 0; hf < 4; ++hf) {
      int r = hf * 16 + lrow;
      int a1 = r * 128 + ((s * 64 + lg * 8) ^ rswz);
      u32x2 lo = *(const u32x2*)(vsm + a1);
      u32x2 hi = *(const u32x2*)(vsm + (a1 ^ 32));
      union { unsigned u[4]; bf16x8 v; } vfu;
      vfu.u[0] = lo.x; vfu.u[1] = lo.y; vfu.u[2] = hi.x; vfu.u[3] = hi.y;
      o[hf] = __builtin_amdgcn_mfma_f32_16x16x32_bf16(vfu.v, pbu[s].v, o[hf], 0, 0, 0);
    }

  float ls = lsl;
  ls += __shfl_xor(ls, 16);
  ls += __shfl_xor(ls, 32);

  size_t rowg = (size_t)blk * NROWS + b * TB + qrow;
  unsigned short* pop = PO + rowg * 64 + lg * 4;
#pragma unroll
  for (int hf = 0; hf < 4; ++hf) {
    u32x2 pk;
    pk.x = pack2bf(o[hf][0], o[hf][1]);
    pk.y = pack2bf(o[hf][2], o[hf][3]);
    *(u32x2*)(pop + hf * 16) = pk;
  }
  if (lg == 0) {
    Mp[rowg] = tmx;
    Lp[rowg] = ls;
  }
}

// ---------------- kernel 2b: combine splits, 32 threads/row ------------------
__global__ void attn_reduce_kernel(const unsigned short* __restrict__ PO,
                                   const float* __restrict__ Mp,
                                   const float* __restrict__ Lp,
                                   float* __restrict__ out) {
  int id = blockIdx.x * 256 + threadIdx.x;
  if (id >= NROWS * 32) return;
  int row = id >> 5, h0 = (id & 31) * 2;
  int t = row & (TB - 1);
  int ns = (t >> 6) + 1; // splits for this row
  float M = -INFINITY;
#pragma unroll 4
  for (int s = 0; s < ns; ++s) M = fmaxf(M, Mp[(size_t)s * NROWS + row]);
  float L = 0.f, a0 = 0.f, a1 = 0.f;
#pragma unroll 4
  for (int s = 0; s < ns; ++s) {
    float w = __expf(Mp[(size_t)s * NROWS + row] - M);
    L += Lp[(size_t)s * NROWS + row] * w;
    unsigned pv = *(const unsigned*)(PO + ((size_t)s * NROWS + row) * 64 + h0);
    a0 += bf2f((unsigned short)(pv & 0xffff)) * w;
    a1 += bf2f((unsigned short)(pv >> 16)) * w;
  }
  float rL = 1.f / L;
  f32x2 r; r.x = a0 * rL; r.y = a1 * rL;
  *(f32x2*)(out + (size_t)row * 64 + h0) = r;
}

extern "C" void kernel_launch(void* const* d_in, const int* in_sizes, int n_in,
                              void* d_out, int out_size, void* d_ws, size_t ws_size,
                              hipStream_t stream) {
  const float* x  = (const float*)d_in[0];
  const float* Wq = (const float*)d_in[1];
  const float* Wk = (const float*)d_in[2];
  const float* Wv = (const float*)d_in[3];
  float* out = (float*)d_out;

  unsigned short* Wt = (unsigned short*)d_ws;
  unsigned short* qb = Wt + 192 * CB;
  unsigned short* kb = qb + (size_t)NROWS * 64;
  unsigned short* vT = kb + (size_t)NROWS * 64;
  char* scratch = (char*)(vT + (size_t)NROWS * 64);

  int SK = SKV;
  unsigned short* part = (unsigned short*)scratch;              // SK*8192*192*2 = 18.9 MB
  unsigned short* PO = (unsigned short*)scratch;                // 32*8192*128 B = 33.6 MB
  float* Mp = (float*)(scratch + (size_t)NSMAX * NROWS * 64 * 2);
  float* Lp = Mp + (size_t)NSMAX * NROWS;

  hipLaunchKernelGGL(cvt_w_kernel, dim3(12, 3), dim3(256), 0, stream,
                     Wq, Wk, Wv, Wt);
  hipLaunchKernelGGL(proj_kernel, dim3(NROWS / 64, SK), dim3(256), 0, stream,
                     x, Wt, part, CB / (64 * SK));
  hipLaunchKernelGGL(reduce_qkv_kernel, dim3(4096 + 512), dim3(256), 0, stream,
                     part, qb, kb, vT, SK);
  hipLaunchKernelGGL(attn_kernel, dim3(WGPB, NB), dim3(256), 0, stream,
                     qb, kb, vT, PO, Mp, Lp);
  hipLaunchKernelGGL(attn_reduce_kernel, dim3((NROWS * 32) / 256), dim3(256), 0, stream,
                     PO, Mp, Lp, out);
}

// Round 14
// 56.759 us; speedup vs baseline: 9.3197x; 1.1022x over previous
//
#include <hip/hip_runtime.h>
#include <math.h>

// B=4, T=2048, C=768, H=64
#define TB 2048
#define CB 768
#define NB 4
#define NROWS (NB * TB) // 8192
#define NSMAX 32        // max KV splits per row (T/64)
#define WGPB 528        // per-batch attn WGs: sum_{g=0..31} (g+1)

typedef __attribute__((ext_vector_type(8))) short bf16x8;
typedef __attribute__((ext_vector_type(4))) float f32x4;
typedef __attribute__((ext_vector_type(2))) float f32x2;
typedef __attribute__((ext_vector_type(2))) unsigned int u32x2;
typedef __attribute__((ext_vector_type(4))) unsigned int u32x4;

__device__ inline unsigned short f2bf(float f) {
  union { float f; unsigned u; } v; v.f = f;
  unsigned r = v.u + 0x7FFFu + ((v.u >> 16) & 1u);
  return (unsigned short)(r >> 16);
}
__device__ inline unsigned pack2bf(float a, float b) {
  return (unsigned)f2bf(a) | ((unsigned)f2bf(b) << 16);
}
__device__ inline float bf2f(unsigned short u) {
  union { unsigned u; float f; } v; v.u = (unsigned)u << 16; return v.f;
}

// ---------------- kernel 0: weights fp32 [C][64] x3 -> Wt bf16 [192][768] ----
__global__ void cvt_w_kernel(const float* __restrict__ Wq, const float* __restrict__ Wk,
                             const float* __restrict__ Wv, unsigned short* __restrict__ Wt) {
  __shared__ float tw[64][65];
  const float* W = (blockIdx.y == 0) ? Wq : (blockIdx.y == 1) ? Wk : Wv;
  const int c0 = blockIdx.x * 64;
  const int row = threadIdx.x >> 2, seg = threadIdx.x & 3;
#pragma unroll
  for (int i = 0; i < 4; ++i) {
    float4 f = *(const float4*)(W + (size_t)(c0 + row) * 64 + seg * 16 + i * 4);
    tw[row][seg * 16 + i * 4 + 0] = f.x;
    tw[row][seg * 16 + i * 4 + 1] = f.y;
    tw[row][seg * 16 + i * 4 + 2] = f.z;
    tw[row][seg * 16 + i * 4 + 3] = f.w;
  }
  __syncthreads();
  const int j = threadIdx.x >> 2, cq = threadIdx.x & 3;
  unsigned short* dst = Wt + (size_t)(blockIdx.y * 64 + j) * CB + c0 + cq * 16;
  u32x4 ua, ub;
#pragma unroll
  for (int i = 0; i < 4; ++i) ua[i] = pack2bf(tw[cq * 16 + 2 * i][j], tw[cq * 16 + 2 * i + 1][j]);
#pragma unroll
  for (int i = 0; i < 4; ++i) ub[i] = pack2bf(tw[cq * 16 + 8 + 2 * i][j], tw[cq * 16 + 9 + 2 * i][j]);
  *(u32x4*)dst = ua;
  *(u32x4*)(dst + 8) = ub;
}

// ---------------- kernel 1: QKV projection, FULL-K, 16-row M-tiles -----------
// grid 512, block 256 (4 waves). Wave wv owns output cols [wv*48, wv*48+48).
// Writes q,k directly; v goes through LDS transpose -> vT.
__launch_bounds__(256)
__global__ void proj_direct_kernel(const float* __restrict__ x,
                                   const unsigned short* __restrict__ Wt,
                                   unsigned short* __restrict__ q,
                                   unsigned short* __restrict__ k,
                                   unsigned short* __restrict__ vT) {
  __shared__ __align__(16) unsigned short xs[16 * 64]; // 16 rows x 64 k, swizzled
  __shared__ float tr[64][17];                         // v transpose staging
  const int tid = threadIdx.x;
  const int wv = tid >> 6;
  const int l = tid & 63;
  const int lrow = l & 15, lg = l >> 4;
  const int m0 = blockIdx.x * 16;
  const int srow = tid >> 4;   // staging row 0..15
  const int sq = tid & 15;     // staging 4-float segment
  const float* xp = x + (size_t)(m0 + srow) * CB + sq * 4;
  const int swz = (srow & 7) << 4;

  f32x4 acc[3];
#pragma unroll
  for (int n = 0; n < 3; ++n) acc[n] = (f32x4){0.f, 0.f, 0.f, 0.f};

  float4 f = *(const float4*)xp; // prefetch k-step 0
  for (int k0 = 0; k0 < CB; k0 += 64) {
    // write current x chunk to LDS bf16 (swizzled), prefetch next
    {
      u32x2 c;
      c.x = pack2bf(f.x, f.y);
      c.y = pack2bf(f.z, f.w);
      *(u32x2*)((char*)xs + srow * 128 + ((sq * 8) ^ swz)) = c;
    }
    if (k0 + 64 < CB) f = *(const float4*)(xp + k0 + 64);
    __syncthreads();

#pragma unroll
    for (int s = 0; s < 2; ++s) {
      bf16x8 af = *(const bf16x8*)((const char*)xs + lrow * 128 +
                                   ((s * 64 + lg * 16) ^ ((lrow & 7) << 4)));
#pragma unroll
      for (int nf = 0; nf < 3; ++nf) {
        int col = wv * 48 + nf * 16 + lrow;
        bf16x8 bfr = *(const bf16x8*)(Wt + (size_t)col * CB + k0 + s * 32 + lg * 8);
        acc[nf] = __builtin_amdgcn_mfma_f32_16x16x32_bf16(af, bfr, acc[nf], 0, 0, 0);
      }
    }
    __syncthreads();
  }

  // epilogue: D row = lg*4 + r (local), col j = wv*48 + nf*16 + lrow
#pragma unroll
  for (int nf = 0; nf < 3; ++nf) {
    int j = wv * 48 + nf * 16 + lrow;
#pragma unroll
    for (int r = 0; r < 4; ++r) {
      int grow = m0 + lg * 4 + r;
      if (j < 64)       q[(size_t)grow * 64 + j] = f2bf(acc[nf][r]);
      else if (j < 128) k[(size_t)grow * 64 + (j - 64)] = f2bf(acc[nf][r]);
      else              tr[j - 128][lg * 4 + r] = acc[nf][r];
    }
  }
  __syncthreads();
  // v writeout: 64 h-rows x 16 t, coalesced 8B per thread
  {
    const int b = m0 >> 11, t0 = m0 & (TB - 1);
    const int h = tid >> 2, tq = tid & 3;
    u32x2 pk;
    pk.x = pack2bf(tr[h][tq * 4 + 0], tr[h][tq * 4 + 1]);
    pk.y = pack2bf(tr[h][tq * 4 + 2], tr[h][tq * 4 + 3]);
    *(u32x2*)(vT + ((size_t)(b * 64 + h)) * TB + t0 + tq * 4) = pk;
  }
}

// ---------------- kernel 2: causal attention, 4 Q-tiles share one KV block ---
__launch_bounds__(256)
__global__ void attn_kernel(const unsigned short* __restrict__ q,
                            const unsigned short* __restrict__ k,
                            const unsigned short* __restrict__ vT,
                            unsigned short* __restrict__ PO, float* __restrict__ Mp,
                            float* __restrict__ Lp) {
  __shared__ __align__(16) char ksm[8192]; // K tile [64 kv][128B], swz (r&7)<<4
  __shared__ __align__(16) char vsm[8192]; // V tile [64 h][128B kv], swz (r&3)<<5
  const int tid = threadIdx.x;
  const int wid = tid >> 6, l = tid & 63;
  const int lrow = l & 15, lg = l >> 4;
  const int b = blockIdx.y;
  const int w = blockIdx.x;

  int g = (int)((sqrtf((float)(8 * w + 1)) - 1.f) * 0.5f);
  while ((g + 1) * (g + 2) / 2 <= w) ++g;
  while (g * (g + 1) / 2 > w) --g;
  const int blk = w - g * (g + 1) / 2;
  const int kv0 = blk * 64;
  const bool last = (blk == g);
  const int qrow = (4 * g + wid) * 16 + lrow;

  const unsigned short* qb = q + (size_t)b * TB * 64;
  const char* kbb = (const char*)(k + (size_t)b * TB * 64);
  const unsigned short* vb = vT + (size_t)b * 64 * TB;

  const int srow = tid >> 2;
  const int sc = (tid & 3) * 32;
  float4 kg0 = *(const float4*)(kbb + (size_t)kv0 * 128 + tid * 32);
  float4 kg1 = *(const float4*)(kbb + (size_t)kv0 * 128 + tid * 32 + 16);
  const char* vrow = (const char*)(vb + (size_t)srow * TB + kv0);
  float4 vg0 = *(const float4*)(vrow + sc);
  float4 vg1 = *(const float4*)(vrow + sc + 16);

  bf16x8 qf[2];
#pragma unroll
  for (int s = 0; s < 2; ++s)
    qf[s] = *(const bf16x8*)(qb + (size_t)qrow * 64 + s * 32 + lg * 8);

  {
    const int kswz_w = (srow & 7) << 4;
    *(float4*)(ksm + srow * 128 + ((sc + 0) ^ kswz_w)) = kg0;
    *(float4*)(ksm + srow * 128 + ((sc + 16) ^ kswz_w)) = kg1;
    const int vswz_w = (srow & 3) << 5;
    *(float4*)(vsm + srow * 128 + ((sc + 0) ^ vswz_w)) = vg0;
    *(float4*)(vsm + srow * 128 + ((sc + 16) ^ vswz_w)) = vg1;
  }
  __syncthreads();

  const int kswz = (lrow & 7) << 4;
  f32x4 S[4];
#pragma unroll
  for (int cf = 0; cf < 4; ++cf) S[cf] = (f32x4){0.f, 0.f, 0.f, 0.f};
#pragma unroll
  for (int cf = 0; cf < 4; ++cf) {
    const char* kp = ksm + (cf * 16 + lrow) * 128;
#pragma unroll
    for (int s = 0; s < 2; ++s) {
      bf16x8 kf = *(const bf16x8*)(kp + ((s * 64 + lg * 16) ^ kswz));
      S[cf] = __builtin_amdgcn_mfma_f32_16x16x32_bf16(kf, qf[s], S[cf], 0, 0, 0);
    }
  }

  const float scale = 0.03608439182435161f; // 768^-0.5
  float tmx = -INFINITY;
#pragma unroll
  for (int cf = 0; cf < 4; ++cf)
#pragma unroll
    for (int r = 0; r < 4; ++r) {
      float vv = S[cf][r] * scale;
      if (last) {
        int kvi = kv0 + cf * 16 + lg * 4 + r;
        vv = (kvi > qrow) ? -INFINITY : vv;
      }
      S[cf][r] = vv;
      tmx = fmaxf(tmx, vv);
    }
  tmx = fmaxf(tmx, __shfl_xor(tmx, 16));
  tmx = fmaxf(tmx, __shfl_xor(tmx, 32)); // row max

  float lsl = 0.f;
  float p[4][4];
#pragma unroll
  for (int cf = 0; cf < 4; ++cf)
#pragma unroll
    for (int r = 0; r < 4; ++r) {
      float pe = __expf(S[cf][r] - tmx);
      p[cf][r] = pe;
      lsl += pe;
    }
  union { unsigned u[4]; bf16x8 v; } pbu[2];
#pragma unroll
  for (int s = 0; s < 2; ++s) {
    pbu[s].u[0] = pack2bf(p[2 * s][0], p[2 * s][1]);
    pbu[s].u[1] = pack2bf(p[2 * s][2], p[2 * s][3]);
    pbu[s].u[2] = pack2bf(p[2 * s + 1][0], p[2 * s + 1][1]);
    pbu[s].u[3] = pack2bf(p[2 * s + 1][2], p[2 * s + 1][3]);
  }

  f32x4 o[4];
#pragma unroll
  for (int hf = 0; hf < 4; ++hf) o[hf] = (f32x4){0.f, 0.f, 0.f, 0.f};
  const int rswz = (lrow & 3) << 5;
#pragma unroll
  for (int s = 0; s < 2; ++s)
#pragma unroll
    for (int hf = 0; hf < 4; ++hf) {
      int r = hf * 16 + lrow;
      int a1 = r * 128 + ((s * 64 + lg * 8) ^ rswz);
      u32x2 lo = *(const u32x2*)(vsm + a1);
      u32x2 hi = *(const u32x2*)(vsm + (a1 ^ 32));
      union { unsigned u[4]; bf16x8 v; } vfu;
      vfu.u[0] = lo.x; vfu.u[1] = lo.y; vfu.u[2] = hi.x; vfu.u[3] = hi.y;
      o[hf] = __builtin_amdgcn_mfma_f32_16x16x32_bf16(vfu.v, pbu[s].v, o[hf], 0, 0, 0);
    }

  float ls = lsl;
  ls += __shfl_xor(ls, 16);
  ls += __shfl_xor(ls, 32);

  size_t rowg = (size_t)blk * NROWS + b * TB + qrow;
  unsigned short* pop = PO + rowg * 64 + lg * 4;
#pragma unroll
  for (int hf = 0; hf < 4; ++hf) {
    u32x2 pk;
    pk.x = pack2bf(o[hf][0], o[hf][1]);
    pk.y = pack2bf(o[hf][2], o[hf][3]);
    *(u32x2*)(pop + hf * 16) = pk;
  }
  if (lg == 0) {
    Mp[rowg] = tmx;
    Lp[rowg] = ls;
  }
}

// ---------------- kernel 2b: combine splits, 32 threads/row ------------------
__global__ void attn_reduce_kernel(const unsigned short* __restrict__ PO,
                                   const float* __restrict__ Mp,
                                   const float* __restrict__ Lp,
                                   float* __restrict__ out) {
  int id = blockIdx.x * 256 + threadIdx.x;
  if (id >= NROWS * 32) return;
  int row = id >> 5, h0 = (id & 31) * 2;
  int t = row & (TB - 1);
  int ns = (t >> 6) + 1; // splits for this row
  float M = -INFINITY;
#pragma unroll 4
  for (int s = 0; s < ns; ++s) M = fmaxf(M, Mp[(size_t)s * NROWS + row]);
  float L = 0.f, a0 = 0.f, a1 = 0.f;
#pragma unroll 4
  for (int s = 0; s < ns; ++s) {
    float w = __expf(Mp[(size_t)s * NROWS + row] - M);
    L += Lp[(size_t)s * NROWS + row] * w;
    unsigned pv = *(const unsigned*)(PO + ((size_t)s * NROWS + row) * 64 + h0);
    a0 += bf2f((unsigned short)(pv & 0xffff)) * w;
    a1 += bf2f((unsigned short)(pv >> 16)) * w;
  }
  float rL = 1.f / L;
  f32x2 r; r.x = a0 * rL; r.y = a1 * rL;
  *(f32x2*)(out + (size_t)row * 64 + h0) = r;
}

extern "C" void kernel_launch(void* const* d_in, const int* in_sizes, int n_in,
                              void* d_out, int out_size, void* d_ws, size_t ws_size,
                              hipStream_t stream) {
  const float* x  = (const float*)d_in[0];
  const float* Wq = (const float*)d_in[1];
  const float* Wk = (const float*)d_in[2];
  const float* Wv = (const float*)d_in[3];
  float* out = (float*)d_out;

  unsigned short* Wt = (unsigned short*)d_ws;
  unsigned short* qb = Wt + 192 * CB;
  unsigned short* kb = qb + (size_t)NROWS * 64;
  unsigned short* vT = kb + (size_t)NROWS * 64;
  char* scratch = (char*)(vT + (size_t)NROWS * 64);

  unsigned short* PO = (unsigned short*)scratch;                // 32*8192*128 B = 33.6 MB
  float* Mp = (float*)(scratch + (size_t)NSMAX * NROWS * 64 * 2);
  float* Lp = Mp + (size_t)NSMAX * NROWS;

  hipLaunchKernelGGL(cvt_w_kernel, dim3(12, 3), dim3(256), 0, stream,
                     Wq, Wk, Wv, Wt);
  hipLaunchKernelGGL(proj_direct_kernel, dim3(NROWS / 16), dim3(256), 0, stream,
                     x, Wt, qb, kb, vT);
  hipLaunchKernelGGL(attn_kernel, dim3(WGPB, NB), dim3(256), 0, stream,
                     qb, kb, vT, PO, Mp, Lp);
  hipLaunchKernelGGL(attn_reduce_kernel, dim3((NROWS * 32) / 256), dim3(256), 0, stream,
                     PO, Mp, Lp, out);
}

// Round 15
// 51.072 us; speedup vs baseline: 10.3574x; 1.1113x over previous
//
#include <hip/hip_runtime.h>
#include <math.h>

// B=4, T=2048, C=768, H=64
#define TB 2048
#define CB 768
#define NB 4
#define NROWS (NB * TB) // 8192
#define NSMAX 16        // max 128-wide KV splits per row
#define WGPB 272        // per-batch attn WGs: sum_{g=0..31} (g/2+1)

typedef __attribute__((ext_vector_type(8))) short bf16x8;
typedef __attribute__((ext_vector_type(4))) float f32x4;
typedef __attribute__((ext_vector_type(2))) float f32x2;
typedef __attribute__((ext_vector_type(2))) unsigned int u32x2;
typedef __attribute__((ext_vector_type(4))) unsigned int u32x4;

__device__ inline unsigned short f2bf(float f) {
  union { float f; unsigned u; } v; v.f = f;
  unsigned r = v.u + 0x7FFFu + ((v.u >> 16) & 1u);
  return (unsigned short)(r >> 16);
}
__device__ inline unsigned pack2bf(float a, float b) {
  return (unsigned)f2bf(a) | ((unsigned)f2bf(b) << 16);
}
__device__ inline float bf2f(unsigned short u) {
  union { unsigned u; float f; } v; v.u = (unsigned)u << 16; return v.f;
}
__device__ inline int groupP(int g) { // #WGs before group g
  int m = g >> 1;
  return (g & 1) ? (m + 1) * (m + 1) : m * (m + 1);
}

// ---------------- kernel 0: weights fp32 [C][64] x3 -> Wt bf16 [192][768] ----
__global__ void cvt_w_kernel(const float* __restrict__ Wq, const float* __restrict__ Wk,
                             const float* __restrict__ Wv, unsigned short* __restrict__ Wt) {
  __shared__ float tw[64][65];
  const float* W = (blockIdx.y == 0) ? Wq : (blockIdx.y == 1) ? Wk : Wv;
  const int c0 = blockIdx.x * 64;
  const int row = threadIdx.x >> 2, seg = threadIdx.x & 3;
#pragma unroll
  for (int i = 0; i < 4; ++i) {
    float4 f = *(const float4*)(W + (size_t)(c0 + row) * 64 + seg * 16 + i * 4);
    tw[row][seg * 16 + i * 4 + 0] = f.x;
    tw[row][seg * 16 + i * 4 + 1] = f.y;
    tw[row][seg * 16 + i * 4 + 2] = f.z;
    tw[row][seg * 16 + i * 4 + 3] = f.w;
  }
  __syncthreads();
  const int j = threadIdx.x >> 2, cq = threadIdx.x & 3;
  unsigned short* dst = Wt + (size_t)(blockIdx.y * 64 + j) * CB + c0 + cq * 16;
  u32x4 ua, ub;
#pragma unroll
  for (int i = 0; i < 4; ++i) ua[i] = pack2bf(tw[cq * 16 + 2 * i][j], tw[cq * 16 + 2 * i + 1][j]);
#pragma unroll
  for (int i = 0; i < 4; ++i) ub[i] = pack2bf(tw[cq * 16 + 8 + 2 * i][j], tw[cq * 16 + 9 + 2 * i][j]);
  *(u32x4*)dst = ua;
  *(u32x4*)(dst + 8) = ub;
}

// ---------------- kernel 1: QKV projection, FULL-K, 16-row M-tiles -----------
__launch_bounds__(256)
__global__ void proj_direct_kernel(const float* __restrict__ x,
                                   const unsigned short* __restrict__ Wt,
                                   unsigned short* __restrict__ q,
                                   unsigned short* __restrict__ k,
                                   unsigned short* __restrict__ vT) {
  __shared__ __align__(16) unsigned short xs[16 * 64];
  __shared__ float tr[64][17];
  const int tid = threadIdx.x;
  const int wv = tid >> 6;
  const int l = tid & 63;
  const int lrow = l & 15, lg = l >> 4;
  const int m0 = blockIdx.x * 16;
  const int srow = tid >> 4;
  const int sq = tid & 15;
  const float* xp = x + (size_t)(m0 + srow) * CB + sq * 4;
  const int swz = (srow & 7) << 4;

  f32x4 acc[3];
#pragma unroll
  for (int n = 0; n < 3; ++n) acc[n] = (f32x4){0.f, 0.f, 0.f, 0.f};

  float4 f = *(const float4*)xp;
  for (int k0 = 0; k0 < CB; k0 += 64) {
    {
      u32x2 c;
      c.x = pack2bf(f.x, f.y);
      c.y = pack2bf(f.z, f.w);
      *(u32x2*)((char*)xs + srow * 128 + ((sq * 8) ^ swz)) = c;
    }
    if (k0 + 64 < CB) f = *(const float4*)(xp + k0 + 64);
    __syncthreads();

#pragma unroll
    for (int s = 0; s < 2; ++s) {
      bf16x8 af = *(const bf16x8*)((const char*)xs + lrow * 128 +
                                   ((s * 64 + lg * 16) ^ ((lrow & 7) << 4)));
#pragma unroll
      for (int nf = 0; nf < 3; ++nf) {
        int col = wv * 48 + nf * 16 + lrow;
        bf16x8 bfr = *(const bf16x8*)(Wt + (size_t)col * CB + k0 + s * 32 + lg * 8);
        acc[nf] = __builtin_amdgcn_mfma_f32_16x16x32_bf16(af, bfr, acc[nf], 0, 0, 0);
      }
    }
    __syncthreads();
  }

#pragma unroll
  for (int nf = 0; nf < 3; ++nf) {
    int j = wv * 48 + nf * 16 + lrow;
#pragma unroll
    for (int r = 0; r < 4; ++r) {
      int grow = m0 + lg * 4 + r;
      if (j < 64)       q[(size_t)grow * 64 + j] = f2bf(acc[nf][r]);
      else if (j < 128) k[(size_t)grow * 64 + (j - 64)] = f2bf(acc[nf][r]);
      else              tr[j - 128][lg * 4 + r] = acc[nf][r];
    }
  }
  __syncthreads();
  {
    const int b = m0 >> 11, t0 = m0 & (TB - 1);
    const int h = tid >> 2, tq = tid & 3;
    u32x2 pk;
    pk.x = pack2bf(tr[h][tq * 4 + 0], tr[h][tq * 4 + 1]);
    pk.y = pack2bf(tr[h][tq * 4 + 2], tr[h][tq * 4 + 3]);
    *(u32x2*)(vT + ((size_t)(b * 64 + h)) * TB + t0 + tq * 4) = pk;
  }
}

// ---------------- kernel 2: causal attention, 128-wide KV splits -------------
// grid (WGPB, B), block 256 (4 waves). WG w -> (g, b128). Tiles 4g..4g+3,
// KV cols [128*b128, 128*b128+128) (second 64-half only if 2*b128+1 <= g).
__launch_bounds__(256)
__global__ void attn_kernel(const unsigned short* __restrict__ q,
                            const unsigned short* __restrict__ k,
                            const unsigned short* __restrict__ vT,
                            unsigned short* __restrict__ PO, float* __restrict__ Mp,
                            float* __restrict__ Lp) {
  __shared__ __align__(16) char ksm[2][8192]; // K sub-tiles, swz (r&7)<<4
  __shared__ __align__(16) char vsm[2][8192]; // V sub-tiles, swz (r&3)<<5
  const int tid = threadIdx.x;
  const int wid = tid >> 6, l = tid & 63;
  const int lrow = l & 15, lg = l >> 4;
  const int b = blockIdx.y;
  const int w = blockIdx.x;

  int g = (int)(2.f * sqrtf((float)w));
  if (g > 31) g = 31;
  while (g < 31 && groupP(g + 1) <= w) ++g;
  while (g > 0 && groupP(g) > w) --g;
  const int b128 = w - groupP(g);
  const int s64a = 2 * b128, s64b = 2 * b128 + 1;
  const bool has1 = (s64b <= g);
  const int kv0a = s64a * 64, kv0b = s64b * 64;
  const int qrow = (4 * g + wid) * 16 + lrow;

  const unsigned short* qb = q + (size_t)b * TB * 64;
  const char* kbb = (const char*)(k + (size_t)b * TB * 64);
  const unsigned short* vb = vT + (size_t)b * 64 * TB;

  const int srow = tid >> 2;
  const int sc = (tid & 3) * 32;
  const int kswz_w = (srow & 7) << 4;
  const int vswz_w = (srow & 3) << 5;

  // --- stage sub-block 0 (always) and 1 (if valid) ---
  float4 ka0 = *(const float4*)(kbb + (size_t)kv0a * 128 + tid * 32);
  float4 ka1 = *(const float4*)(kbb + (size_t)kv0a * 128 + tid * 32 + 16);
  const char* vrowa = (const char*)(vb + (size_t)srow * TB + kv0a);
  float4 va0 = *(const float4*)(vrowa + sc);
  float4 va1 = *(const float4*)(vrowa + sc + 16);

  bf16x8 qf[2];
#pragma unroll
  for (int s = 0; s < 2; ++s)
    qf[s] = *(const bf16x8*)(qb + (size_t)qrow * 64 + s * 32 + lg * 8);

  *(float4*)(ksm[0] + srow * 128 + ((sc + 0) ^ kswz_w)) = ka0;
  *(float4*)(ksm[0] + srow * 128 + ((sc + 16) ^ kswz_w)) = ka1;
  *(float4*)(vsm[0] + srow * 128 + ((sc + 0) ^ vswz_w)) = va0;
  *(float4*)(vsm[0] + srow * 128 + ((sc + 16) ^ vswz_w)) = va1;

  if (has1) {
    float4 kb0 = *(const float4*)(kbb + (size_t)kv0b * 128 + tid * 32);
    float4 kb1 = *(const float4*)(kbb + (size_t)kv0b * 128 + tid * 32 + 16);
    const char* vrowb = (const char*)(vb + (size_t)srow * TB + kv0b);
    float4 vb0 = *(const float4*)(vrowb + sc);
    float4 vb1 = *(const float4*)(vrowb + sc + 16);
    *(float4*)(ksm[1] + srow * 128 + ((sc + 0) ^ kswz_w)) = kb0;
    *(float4*)(ksm[1] + srow * 128 + ((sc + 16) ^ kswz_w)) = kb1;
    *(float4*)(vsm[1] + srow * 128 + ((sc + 0) ^ vswz_w)) = vb0;
    *(float4*)(vsm[1] + srow * 128 + ((sc + 16) ^ vswz_w)) = vb1;
  }
  __syncthreads();

  const int kswz = (lrow & 7) << 4;
  const float scale = 0.03608439182435161f; // 768^-0.5

  // --- QK^T sub-block 0 ---
  f32x4 S0[4];
#pragma unroll
  for (int cf = 0; cf < 4; ++cf) S0[cf] = (f32x4){0.f, 0.f, 0.f, 0.f};
#pragma unroll
  for (int cf = 0; cf < 4; ++cf) {
    const char* kp = ksm[0] + (cf * 16 + lrow) * 128;
#pragma unroll
    for (int s = 0; s < 2; ++s) {
      bf16x8 kf = *(const bf16x8*)(kp + ((s * 64 + lg * 16) ^ kswz));
      S0[cf] = __builtin_amdgcn_mfma_f32_16x16x32_bf16(kf, qf[s], S0[cf], 0, 0, 0);
    }
  }
  float tmx = -INFINITY;
  {
    const bool msk = (s64a == g);
#pragma unroll
    for (int cf = 0; cf < 4; ++cf)
#pragma unroll
      for (int r = 0; r < 4; ++r) {
        float vv = S0[cf][r] * scale;
        if (msk) {
          int kvi = kv0a + cf * 16 + lg * 4 + r;
          vv = (kvi > qrow) ? -INFINITY : vv;
        }
        S0[cf][r] = vv;
        tmx = fmaxf(tmx, vv);
      }
  }
  // --- QK^T sub-block 1 ---
  f32x4 S1[4];
  if (has1) {
#pragma unroll
    for (int cf = 0; cf < 4; ++cf) S1[cf] = (f32x4){0.f, 0.f, 0.f, 0.f};
#pragma unroll
    for (int cf = 0; cf < 4; ++cf) {
      const char* kp = ksm[1] + (cf * 16 + lrow) * 128;
#pragma unroll
      for (int s = 0; s < 2; ++s) {
        bf16x8 kf = *(const bf16x8*)(kp + ((s * 64 + lg * 16) ^ kswz));
        S1[cf] = __builtin_amdgcn_mfma_f32_16x16x32_bf16(kf, qf[s], S1[cf], 0, 0, 0);
      }
    }
    const bool msk = (s64b == g);
#pragma unroll
    for (int cf = 0; cf < 4; ++cf)
#pragma unroll
      for (int r = 0; r < 4; ++r) {
        float vv = S1[cf][r] * scale;
        if (msk) {
          int kvi = kv0b + cf * 16 + lg * 4 + r;
          vv = (kvi > qrow) ? -INFINITY : vv;
        }
        S1[cf][r] = vv;
        tmx = fmaxf(tmx, vv);
      }
  }
  tmx = fmaxf(tmx, __shfl_xor(tmx, 16));
  tmx = fmaxf(tmx, __shfl_xor(tmx, 32)); // joint row max over 128 cols

  float lsl = 0.f;
  f32x4 o[4];
#pragma unroll
  for (int hf = 0; hf < 4; ++hf) o[hf] = (f32x4){0.f, 0.f, 0.f, 0.f};
  const int rswz = (lrow & 3) << 5;

  // --- softmax + PV sub-block 0 ---
  {
    float p[4][4];
#pragma unroll
    for (int cf = 0; cf < 4; ++cf)
#pragma unroll
      for (int r = 0; r < 4; ++r) {
        float pe = __expf(S0[cf][r] - tmx);
        p[cf][r] = pe;
        lsl += pe;
      }
    union { unsigned u[4]; bf16x8 v; } pbu[2];
#pragma unroll
    for (int s = 0; s < 2; ++s) {
      pbu[s].u[0] = pack2bf(p[2 * s][0], p[2 * s][1]);
      pbu[s].u[1] = pack2bf(p[2 * s][2], p[2 * s][3]);
      pbu[s].u[2] = pack2bf(p[2 * s + 1][0], p[2 * s + 1][1]);
      pbu[s].u[3] = pack2bf(p[2 * s + 1][2], p[2 * s + 1][3]);
    }
#pragma unroll
    for (int s = 0; s < 2; ++s)
#pragma unroll
      for (int hf = 0; hf < 4; ++hf) {
        int r = hf * 16 + lrow;
        int a1 = r * 128 + ((s * 64 + lg * 8) ^ rswz);
        u32x2 lo = *(const u32x2*)(vsm[0] + a1);
        u32x2 hi = *(const u32x2*)(vsm[0] + (a1 ^ 32));
        union { unsigned u[4]; bf16x8 v; } vfu;
        vfu.u[0] = lo.x; vfu.u[1] = lo.y; vfu.u[2] = hi.x; vfu.u[3] = hi.y;
        o[hf] = __builtin_amdgcn_mfma_f32_16x16x32_bf16(vfu.v, pbu[s].v, o[hf], 0, 0, 0);
      }
  }
  // --- softmax + PV sub-block 1 ---
  if (has1) {
    float p[4][4];
#pragma unroll
    for (int cf = 0; cf < 4; ++cf)
#pragma unroll
      for (int r = 0; r < 4; ++r) {
        float pe = __expf(S1[cf][r] - tmx);
        p[cf][r] = pe;
        lsl += pe;
      }
    union { unsigned u[4]; bf16x8 v; } pbu[2];
#pragma unroll
    for (int s = 0; s < 2; ++s) {
      pbu[s].u[0] = pack2bf(p[2 * s][0], p[2 * s][1]);
      pbu[s].u[1] = pack2bf(p[2 * s][2], p[2 * s][3]);
      pbu[s].u[2] = pack2bf(p[2 * s + 1][0], p[2 * s + 1][1]);
      pbu[s].u[3] = pack2bf(p[2 * s + 1][2], p[2 * s + 1][3]);
    }
#pragma unroll
    for (int s = 0; s < 2; ++s)
#pragma unroll
      for (int hf = 0; hf < 4; ++hf) {
        int r = hf * 16 + lrow;
        int a1 = r * 128 + ((s * 64 + lg * 8) ^ rswz);
        u32x2 lo = *(const u32x2*)(vsm[1] + a1);
        u32x2 hi = *(const u32x2*)(vsm[1] + (a1 ^ 32));
        union { unsigned u[4]; bf16x8 v; } vfu;
        vfu.u[0] = lo.x; vfu.u[1] = lo.y; vfu.u[2] = hi.x; vfu.u[3] = hi.y;
        o[hf] = __builtin_amdgcn_mfma_f32_16x16x32_bf16(vfu.v, pbu[s].v, o[hf], 0, 0, 0);
      }
  }

  float ls = lsl;
  ls += __shfl_xor(ls, 16);
  ls += __shfl_xor(ls, 32);

  // split-major partial write, plane = b128
  size_t rowg = (size_t)b128 * NROWS + b * TB + qrow;
  unsigned short* pop = PO + rowg * 64 + lg * 4;
#pragma unroll
  for (int hf = 0; hf < 4; ++hf) {
    u32x2 pk;
    pk.x = pack2bf(o[hf][0], o[hf][1]);
    pk.y = pack2bf(o[hf][2], o[hf][3]);
    *(u32x2*)(pop + hf * 16) = pk;
  }
  if (lg == 0) {
    Mp[rowg] = tmx;
    Lp[rowg] = ls;
  }
}

// ---------------- kernel 2b: combine splits, 32 threads/row ------------------
__global__ void attn_reduce_kernel(const unsigned short* __restrict__ PO,
                                   const float* __restrict__ Mp,
                                   const float* __restrict__ Lp,
                                   float* __restrict__ out) {
  int id = blockIdx.x * 256 + threadIdx.x;
  if (id >= NROWS * 32) return;
  int row = id >> 5, h0 = (id & 31) * 2;
  int t = row & (TB - 1);
  int ns = (t >> 7) + 1; // 128-wide splits for this row
  float M = -INFINITY;
#pragma unroll 4
  for (int s = 0; s < ns; ++s) M = fmaxf(M, Mp[(size_t)s * NROWS + row]);
  float L = 0.f, a0 = 0.f, a1 = 0.f;
#pragma unroll 4
  for (int s = 0; s < ns; ++s) {
    float w = __expf(Mp[(size_t)s * NROWS + row] - M);
    L += Lp[(size_t)s * NROWS + row] * w;
    unsigned pv = *(const unsigned*)(PO + ((size_t)s * NROWS + row) * 64 + h0);
    a0 += bf2f((unsigned short)(pv & 0xffff)) * w;
    a1 += bf2f((unsigned short)(pv >> 16)) * w;
  }
  float rL = 1.f / L;
  f32x2 r; r.x = a0 * rL; r.y = a1 * rL;
  *(f32x2*)(out + (size_t)row * 64 + h0) = r;
}

extern "C" void kernel_launch(void* const* d_in, const int* in_sizes, int n_in,
                              void* d_out, int out_size, void* d_ws, size_t ws_size,
                              hipStream_t stream) {
  const float* x  = (const float*)d_in[0];
  const float* Wq = (const float*)d_in[1];
  const float* Wk = (const float*)d_in[2];
  const float* Wv = (const float*)d_in[3];
  float* out = (float*)d_out;

  unsigned short* Wt = (unsigned short*)d_ws;
  unsigned short* qb = Wt + 192 * CB;
  unsigned short* kb = qb + (size_t)NROWS * 64;
  unsigned short* vT = kb + (size_t)NROWS * 64;
  char* scratch = (char*)(vT + (size_t)NROWS * 64);

  unsigned short* PO = (unsigned short*)scratch;                // 16*8192*128 B = 16.8 MB
  float* Mp = (float*)(scratch + (size_t)NSMAX * NROWS * 64 * 2);
  float* Lp = Mp + (size_t)NSMAX * NROWS;

  hipLaunchKernelGGL(cvt_w_kernel, dim3(12, 3), dim3(256), 0, stream,
                     Wq, Wk, Wv, Wt);
  hipLaunchKernelGGL(proj_direct_kernel, dim3(NROWS / 16), dim3(256), 0, stream,
                     x, Wt, qb, kb, vT);
  hipLaunchKernelGGL(attn_kernel, dim3(WGPB, NB), dim3(256), 0, stream,
                     qb, kb, vT, PO, Mp, Lp);
  hipLaunchKernelGGL(attn_reduce_kernel, dim3((NROWS * 32) / 256), dim3(256), 0, stream,
                     PO, Mp, Lp, out);
}

// Round 17
// 50.984 us; speedup vs baseline: 10.3753x; 1.0017x over previous
//
#include <hip/hip_runtime.h>
#include <math.h>

// B=4, T=2048, C=768, H=64
#define TB 2048
#define CB 768
#define NB 4
#define NROWS (NB * TB) // 8192
#define NSMAX 16        // max 128-wide KV splits per row
#define WGPB 136        // per-batch attn WGs: sum_{g=0..15} (g+1)

typedef __attribute__((ext_vector_type(8))) short bf16x8;
typedef __attribute__((ext_vector_type(4))) float f32x4;
typedef __attribute__((ext_vector_type(2))) float f32x2;
typedef __attribute__((ext_vector_type(2))) unsigned int u32x2;
typedef __attribute__((ext_vector_type(4))) unsigned int u32x4;

__device__ inline unsigned short f2bf(float f) {
  union { float f; unsigned u; } v; v.f = f;
  unsigned r = v.u + 0x7FFFu + ((v.u >> 16) & 1u);
  return (unsigned short)(r >> 16);
}
__device__ inline unsigned pack2bf(float a, float b) {
  return (unsigned)f2bf(a) | ((unsigned)f2bf(b) << 16);
}
__device__ inline float bf2f(unsigned short u) {
  union { unsigned u; float f; } v; v.u = (unsigned)u << 16; return v.f;
}

// ---------------- kernel 0: weights fp32 [C][64] x3 -> Wt bf16 [192][768] ----
__global__ void cvt_w_kernel(const float* __restrict__ Wq, const float* __restrict__ Wk,
                             const float* __restrict__ Wv, unsigned short* __restrict__ Wt) {
  __shared__ float tw[64][65];
  const float* W = (blockIdx.y == 0) ? Wq : (blockIdx.y == 1) ? Wk : Wv;
  const int c0 = blockIdx.x * 64;
  const int row = threadIdx.x >> 2, seg = threadIdx.x & 3;
#pragma unroll
  for (int i = 0; i < 4; ++i) {
    float4 f = *(const float4*)(W + (size_t)(c0 + row) * 64 + seg * 16 + i * 4);
    tw[row][seg * 16 + i * 4 + 0] = f.x;
    tw[row][seg * 16 + i * 4 + 1] = f.y;
    tw[row][seg * 16 + i * 4 + 2] = f.z;
    tw[row][seg * 16 + i * 4 + 3] = f.w;
  }
  __syncthreads();
  const int j = threadIdx.x >> 2, cq = threadIdx.x & 3;
  unsigned short* dst = Wt + (size_t)(blockIdx.y * 64 + j) * CB + c0 + cq * 16;
  u32x4 ua, ub;
#pragma unroll
  for (int i = 0; i < 4; ++i) ua[i] = pack2bf(tw[cq * 16 + 2 * i][j], tw[cq * 16 + 2 * i + 1][j]);
#pragma unroll
  for (int i = 0; i < 4; ++i) ub[i] = pack2bf(tw[cq * 16 + 8 + 2 * i][j], tw[cq * 16 + 9 + 2 * i][j]);
  *(u32x4*)dst = ua;
  *(u32x4*)(dst + 8) = ub;
}

// ---------------- kernel 1: QKV projection, FULL-K, 16-row M-tiles -----------
__launch_bounds__(256)
__global__ void proj_direct_kernel(const float* __restrict__ x,
                                   const unsigned short* __restrict__ Wt,
                                   unsigned short* __restrict__ q,
                                   unsigned short* __restrict__ k,
                                   unsigned short* __restrict__ vT) {
  __shared__ __align__(16) unsigned short xs[16 * 64];
  __shared__ float tr[64][17];
  const int tid = threadIdx.x;
  const int wv = tid >> 6;
  const int l = tid & 63;
  const int lrow = l & 15, lg = l >> 4;
  const int m0 = blockIdx.x * 16;
  const int srow = tid >> 4;
  const int sq = tid & 15;
  const float* xp = x + (size_t)(m0 + srow) * CB + sq * 4;
  const int swz = (srow & 7) << 4;

  f32x4 acc[3];
#pragma unroll
  for (int n = 0; n < 3; ++n) acc[n] = (f32x4){0.f, 0.f, 0.f, 0.f};

  float4 f = *(const float4*)xp;
  for (int k0 = 0; k0 < CB; k0 += 64) {
    {
      u32x2 c;
      c.x = pack2bf(f.x, f.y);
      c.y = pack2bf(f.z, f.w);
      *(u32x2*)((char*)xs + srow * 128 + ((sq * 8) ^ swz)) = c;
    }
    if (k0 + 64 < CB) f = *(const float4*)(xp + k0 + 64);
    __syncthreads();

#pragma unroll
    for (int s = 0; s < 2; ++s) {
      bf16x8 af = *(const bf16x8*)((const char*)xs + lrow * 128 +
                                   ((s * 64 + lg * 16) ^ ((lrow & 7) << 4)));
#pragma unroll
      for (int nf = 0; nf < 3; ++nf) {
        int col = wv * 48 + nf * 16 + lrow;
        bf16x8 bfr = *(const bf16x8*)(Wt + (size_t)col * CB + k0 + s * 32 + lg * 8);
        acc[nf] = __builtin_amdgcn_mfma_f32_16x16x32_bf16(af, bfr, acc[nf], 0, 0, 0);
      }
    }
    __syncthreads();
  }

#pragma unroll
  for (int nf = 0; nf < 3; ++nf) {
    int j = wv * 48 + nf * 16 + lrow;
#pragma unroll
    for (int r = 0; r < 4; ++r) {
      int grow = m0 + lg * 4 + r;
      if (j < 64)       q[(size_t)grow * 64 + j] = f2bf(acc[nf][r]);
      else if (j < 128) k[(size_t)grow * 64 + (j - 64)] = f2bf(acc[nf][r]);
      else              tr[j - 128][lg * 4 + r] = acc[nf][r];
    }
  }
  __syncthreads();
  {
    const int b = m0 >> 11, t0 = m0 & (TB - 1);
    const int h = tid >> 2, tq = tid & 3;
    u32x2 pk;
    pk.x = pack2bf(tr[h][tq * 4 + 0], tr[h][tq * 4 + 1]);
    pk.y = pack2bf(tr[h][tq * 4 + 2], tr[h][tq * 4 + 3]);
    *(u32x2*)(vT + ((size_t)(b * 64 + h)) * TB + t0 + tq * 4) = pk;
  }
}

// ---------------- kernel 2: causal attention, 8 Q-tiles x 128-wide KV --------
// grid (WGPB, B), block 512 (8 waves). WG w -> (g, b128), b128 in [0, g].
// Wave wid handles tile t = 8g+wid (rows [16t,16t+16)); KV cols
// [128*b128, 128*b128+128) staged once in LDS, shared by all 8 waves.
__launch_bounds__(512)
__global__ void attn_kernel(const unsigned short* __restrict__ q,
                            const unsigned short* __restrict__ k,
                            const unsigned short* __restrict__ vT,
                            unsigned short* __restrict__ PO, float* __restrict__ Mp,
                            float* __restrict__ Lp) {
  __shared__ __align__(16) char ksm[2][8192]; // K sub-tiles, swz (r&7)<<4
  __shared__ __align__(16) char vsm[2][8192]; // V sub-tiles, swz (r&3)<<5
  const int tid = threadIdx.x;
  const int wid = tid >> 6, l = tid & 63;
  const int lrow = l & 15, lg = l >> 4;
  const int b = blockIdx.y;
  const int w = blockIdx.x;

  // decode triangular index: g s.t. g(g+1)/2 <= w < (g+1)(g+2)/2 (g in [0,15])
  int g = (int)((sqrtf((float)(8 * w + 1)) - 1.f) * 0.5f);
  while ((g + 1) * (g + 2) / 2 <= w) ++g;
  while (g * (g + 1) / 2 > w) --g;
  const int b128 = w - g * (g + 1) / 2;
  const int kv0a = b128 * 128, kv0b = kv0a + 64;
  const int t = 8 * g + wid;       // this wave's Q-tile
  const int q0w = t * 16;
  const int qrow = q0w + lrow;

  const unsigned short* qb = q + (size_t)b * TB * 64;
  const char* kbb = (const char*)(k + (size_t)b * TB * 64);
  const unsigned short* vb = vT + (size_t)b * 64 * TB;

  // --- cooperative staging: 512 threads, 16B/thread per sub-tile ---
  const int srow = tid >> 3;            // 0..63
  const int sc = (tid & 7) * 16;        // byte offset within 128B row
  const int kswz_w = (srow & 7) << 4;
  const int vswz_w = (srow & 3) << 5;
  float4 ka = *(const float4*)(kbb + (size_t)kv0a * 128 + tid * 16);
  float4 kb2 = *(const float4*)(kbb + (size_t)kv0b * 128 + tid * 16);
  float4 va = *(const float4*)((const char*)(vb + (size_t)srow * TB + kv0a) + sc);
  float4 vb2 = *(const float4*)((const char*)(vb + (size_t)srow * TB + kv0b) + sc);

  bf16x8 qf[2];
#pragma unroll
  for (int s = 0; s < 2; ++s)
    qf[s] = *(const bf16x8*)(qb + (size_t)qrow * 64 + s * 32 + lg * 8);

  *(float4*)(ksm[0] + srow * 128 + (sc ^ kswz_w)) = ka;
  *(float4*)(ksm[1] + srow * 128 + (sc ^ kswz_w)) = kb2;
  *(float4*)(vsm[0] + srow * 128 + (sc ^ vswz_w)) = va;
  *(float4*)(vsm[1] + srow * 128 + (sc ^ vswz_w)) = vb2;
  __syncthreads();

  const int kswz = (lrow & 7) << 4;
  const float scale = 0.03608439182435161f; // 768^-0.5
  const bool useb = (kv0b <= q0w + 15);     // second sub-block below diagonal?

  // --- QK^T sub-block 0 ---
  f32x4 S0[4];
#pragma unroll
  for (int cf = 0; cf < 4; ++cf) S0[cf] = (f32x4){0.f, 0.f, 0.f, 0.f};
#pragma unroll
  for (int cf = 0; cf < 4; ++cf) {
    const char* kp = ksm[0] + (cf * 16 + lrow) * 128;
#pragma unroll
    for (int s = 0; s < 2; ++s) {
      bf16x8 kf = *(const bf16x8*)(kp + ((s * 64 + lg * 16) ^ kswz));
      S0[cf] = __builtin_amdgcn_mfma_f32_16x16x32_bf16(kf, qf[s], S0[cf], 0, 0, 0);
    }
  }
  float tmx = -INFINITY;
  {
    const bool msk = (kv0a + 63 > q0w); // mask iff max col can exceed MIN row
#pragma unroll
    for (int cf = 0; cf < 4; ++cf)
#pragma unroll
      for (int r = 0; r < 4; ++r) {
        float vv = S0[cf][r] * scale;
        if (msk) {
          int kvi = kv0a + cf * 16 + lg * 4 + r;
          vv = (kvi > qrow) ? -INFINITY : vv;
        }
        S0[cf][r] = vv;
        tmx = fmaxf(tmx, vv);
      }
  }
  // --- QK^T sub-block 1 (wave-uniform skip above diagonal) ---
  f32x4 S1[4];
  if (useb) {
#pragma unroll
    for (int cf = 0; cf < 4; ++cf) S1[cf] = (f32x4){0.f, 0.f, 0.f, 0.f};
#pragma unroll
    for (int cf = 0; cf < 4; ++cf) {
      const char* kp = ksm[1] + (cf * 16 + lrow) * 128;
#pragma unroll
      for (int s = 0; s < 2; ++s) {
        bf16x8 kf = *(const bf16x8*)(kp + ((s * 64 + lg * 16) ^ kswz));
        S1[cf] = __builtin_amdgcn_mfma_f32_16x16x32_bf16(kf, qf[s], S1[cf], 0, 0, 0);
      }
    }
    const bool msk = (kv0b + 63 > q0w); // mask iff max col can exceed MIN row
#pragma unroll
    for (int cf = 0; cf < 4; ++cf)
#pragma unroll
      for (int r = 0; r < 4; ++r) {
        float vv = S1[cf][r] * scale;
        if (msk) {
          int kvi = kv0b + cf * 16 + lg * 4 + r;
          vv = (kvi > qrow) ? -INFINITY : vv;
        }
        S1[cf][r] = vv;
        tmx = fmaxf(tmx, vv);
      }
  }
  tmx = fmaxf(tmx, __shfl_xor(tmx, 16));
  tmx = fmaxf(tmx, __shfl_xor(tmx, 32)); // joint row max

  float lsl = 0.f;
  f32x4 o[4];
#pragma unroll
  for (int hf = 0; hf < 4; ++hf) o[hf] = (f32x4){0.f, 0.f, 0.f, 0.f};
  const int rswz = (lrow & 3) << 5;

  // --- softmax + PV sub-block 0 ---
  {
    float p[4][4];
#pragma unroll
    for (int cf = 0; cf < 4; ++cf)
#pragma unroll
      for (int r = 0; r < 4; ++r) {
        float pe = __expf(S0[cf][r] - tmx);
        p[cf][r] = pe;
        lsl += pe;
      }
    union { unsigned u[4]; bf16x8 v; } pbu[2];
#pragma unroll
    for (int s = 0; s < 2; ++s) {
      pbu[s].u[0] = pack2bf(p[2 * s][0], p[2 * s][1]);
      pbu[s].u[1] = pack2bf(p[2 * s][2], p[2 * s][3]);
      pbu[s].u[2] = pack2bf(p[2 * s + 1][0], p[2 * s + 1][1]);
      pbu[s].u[3] = pack2bf(p[2 * s + 1][2], p[2 * s + 1][3]);
    }
#pragma unroll
    for (int s = 0; s < 2; ++s)
#pragma unroll
      for (int hf = 0; hf < 4; ++hf) {
        int r = hf * 16 + lrow;
        int a1 = r * 128 + ((s * 64 + lg * 8) ^ rswz);
        u32x2 lo = *(const u32x2*)(vsm[0] + a1);
        u32x2 hi = *(const u32x2*)(vsm[0] + (a1 ^ 32));
        union { unsigned u[4]; bf16x8 v; } vfu;
        vfu.u[0] = lo.x; vfu.u[1] = lo.y; vfu.u[2] = hi.x; vfu.u[3] = hi.y;
        o[hf] = __builtin_amdgcn_mfma_f32_16x16x32_bf16(vfu.v, pbu[s].v, o[hf], 0, 0, 0);
      }
  }
  // --- softmax + PV sub-block 1 ---
  if (useb) {
    float p[4][4];
#pragma unroll
    for (int cf = 0; cf < 4; ++cf)
#pragma unroll
      for (int r = 0; r < 4; ++r) {
        float pe = __expf(S1[cf][r] - tmx);
        p[cf][r] = pe;
        lsl += pe;
      }
    union { unsigned u[4]; bf16x8 v; } pbu[2];
#pragma unroll
    for (int s = 0; s < 2; ++s) {
      pbu[s].u[0] = pack2bf(p[2 * s][0], p[2 * s][1]);
      pbu[s].u[1] = pack2bf(p[2 * s][2], p[2 * s][3]);
      pbu[s].u[2] = pack2bf(p[2 * s + 1][0], p[2 * s + 1][1]);
      pbu[s].u[3] = pack2bf(p[2 * s + 1][2], p[2 * s + 1][3]);
    }
#pragma unroll
    for (int s = 0; s < 2; ++s)
#pragma unroll
      for (int hf = 0; hf < 4; ++hf) {
        int r = hf * 16 + lrow;
        int a1 = r * 128 + ((s * 64 + lg * 8) ^ rswz);
        u32x2 lo = *(const u32x2*)(vsm[1] + a1);
        u32x2 hi = *(const u32x2*)(vsm[1] + (a1 ^ 32));
        union { unsigned u[4]; bf16x8 v; } vfu;
        vfu.u[0] = lo.x; vfu.u[1] = lo.y; vfu.u[2] = hi.x; vfu.u[3] = hi.y;
        o[hf] = __builtin_amdgcn_mfma_f32_16x16x32_bf16(vfu.v, pbu[s].v, o[hf], 0, 0, 0);
      }
  }

  float ls = lsl;
  ls += __shfl_xor(ls, 16);
  ls += __shfl_xor(ls, 32);

  // split-major partial write, plane = b128
  size_t rowg = (size_t)b128 * NROWS + b * TB + qrow;
  unsigned short* pop = PO + rowg * 64 + lg * 4;
#pragma unroll
  for (int hf = 0; hf < 4; ++hf) {
    u32x2 pk;
    pk.x = pack2bf(o[hf][0], o[hf][1]);
    pk.y = pack2bf(o[hf][2], o[hf][3]);
    *(u32x2*)(pop + hf * 16) = pk;
  }
  if (lg == 0) {
    Mp[rowg] = tmx;
    Lp[rowg] = ls;
  }
}

// ---------------- kernel 2b: combine splits, 32 threads/row ------------------
__global__ void attn_reduce_kernel(const unsigned short* __restrict__ PO,
                                   const float* __restrict__ Mp,
                                   const float* __restrict__ Lp,
                                   float* __restrict__ out) {
  int id = blockIdx.x * 256 + threadIdx.x;
  if (id >= NROWS * 32) return;
  int row = id >> 5, h0 = (id & 31) * 2;
  int t = row & (TB - 1);
  int ns = (t >> 7) + 1; // 128-wide splits for this row
  float M = -INFINITY;
#pragma unroll 4
  for (int s = 0; s < ns; ++s) M = fmaxf(M, Mp[(size_t)s * NROWS + row]);
  float L = 0.f, a0 = 0.f, a1 = 0.f;
#pragma unroll 4
  for (int s = 0; s < ns; ++s) {
    float w = __expf(Mp[(size_t)s * NROWS + row] - M);
    L += Lp[(size_t)s * NROWS + row] * w;
    unsigned pv = *(const unsigned*)(PO + ((size_t)s * NROWS + row) * 64 + h0);
    a0 += bf2f((unsigned short)(pv & 0xffff)) * w;
    a1 += bf2f((unsigned short)(pv >> 16)) * w;
  }
  float rL = 1.f / L;
  f32x2 r; r.x = a0 * rL; r.y = a1 * rL;
  *(f32x2*)(out + (size_t)row * 64 + h0) = r;
}

extern "C" void kernel_launch(void* const* d_in, const int* in_sizes, int n_in,
                              void* d_out, int out_size, void* d_ws, size_t ws_size,
                              hipStream_t stream) {
  const float* x  = (const float*)d_in[0];
  const float* Wq = (const float*)d_in[1];
  const float* Wk = (const float*)d_in[2];
  const float* Wv = (const float*)d_in[3];
  float* out = (float*)d_out;

  unsigned short* Wt = (unsigned short*)d_ws;
  unsigned short* qb = Wt + 192 * CB;
  unsigned short* kb = qb + (size_t)NROWS * 64;
  unsigned short* vT = kb + (size_t)NROWS * 64;
  char* scratch = (char*)(vT + (size_t)NROWS * 64);

  unsigned short* PO = (unsigned short*)scratch;                // 16*8192*128 B = 16.8 MB
  float* Mp = (float*)(scratch + (size_t)NSMAX * NROWS * 64 * 2);
  float* Lp = Mp + (size_t)NSMAX * NROWS;

  hipLaunchKernelGGL(cvt_w_kernel, dim3(12, 3), dim3(256), 0, stream,
                     Wq, Wk, Wv, Wt);
  hipLaunchKernelGGL(proj_direct_kernel, dim3(NROWS / 16), dim3(256), 0, stream,
                     x, Wt, qb, kb, vT);
  hipLaunchKernelGGL(attn_kernel, dim3(WGPB, NB), dim3(512), 0, stream,
                     qb, kb, vT, PO, Mp, Lp);
  hipLaunchKernelGGL(attn_reduce_kernel, dim3((NROWS * 32) / 256), dim3(256), 0, stream,
                     PO, Mp, Lp, out);
}